// Round 13
// baseline (49.781 us; speedup 1.0000x reference)
//
#include <hip/hip_runtime.h>

#define C_NUM   256
#define K_CODES 4096
#define D_CB    8
#define THREADS 1024
#define NWAVES  16
#define TPW     4                   // tuples per wave; 16 waves x 4 = 64 tuples/block
#define CHUNKS  64                  // every wave scans all 4096 codes, 64/chunk

typedef float v2f __attribute__((ext_vector_type(2)));

// packed fp32 FMA: d = x * bcast(key-half) + d, tuple-pair in the two halves.
#define PK_INIT(d, x, kp, c) \
    asm("v_pk_fma_f32 %0, %1, %2, %3 op_sel:[0,0,0] op_sel_hi:[1,0,1]" \
        : "=v"(d) : "v"(x), "v"(kp), "v"(c))
#define PK_LO(d, x, kp) \
    asm("v_pk_fma_f32 %0, %1, %2, %0 op_sel:[0,0,0] op_sel_hi:[1,0,1]" \
        : "+v"(d) : "v"(x), "v"(kp))
#define PK_HI(d, x, kp) \
    asm("v_pk_fma_f32 %0, %1, %2, %0 op_sel:[0,1,0] op_sel_hi:[1,1,1]" \
        : "+v"(d) : "v"(x), "v"(kp))

__global__ __launch_bounds__(THREADS)   // 1024-thr: allocator targets 64 VGPR; body needs ~56-60
void dkvb_kernel(const float* __restrict__ emb,
                 const float* __restrict__ keys,
                 const float* __restrict__ values,
                 float* __restrict__ out) {
    __shared__ float xs[64][D_CB];   // 2 KB

    const int bid  = blockIdx.x;
    const int c    = bid & 255;      // codebook; bid and bid+256 share an XCD (256%8==0)
    const int h    = bid >> 8;       // tuple half: 0 -> tuples 0..63, 1 -> 64..127
    const int tid  = threadIdx.x;
    const int wave = tid >> 6;
    const int lane = tid & 63;

    // ---- stage this block's 64 tuples of x into LDS (one element/thread) ----
    // x[t][j] = emb[(t>>4)*32768 + c*128 + j*16 + (t&15)]
    if (tid < 512) {
        const int tl = tid >> 3, j = tid & 7;
        const int tg = h * 64 + tl;
        xs[tl][j] = emb[(size_t)(tg >> 4) * 32768 + c * 128 + j * 16 + (tg & 15)];
    }
    __syncthreads();

    // ---- x' = -2*x, tuple-PAIRED into VGPR float2s: xp[u][j] = (x'[4w+2u], x'[4w+2u+1]) ----
    v2f xp[2][8];
    #pragma unroll
    for (int u = 0; u < 2; ++u) {
        #pragma unroll
        for (int j = 0; j < 8; ++j) {
            v2f p;
            p.x = -2.0f * xs[wave * TPW + 2 * u][j];
            p.y = -2.0f * xs[wave * TPW + 2 * u + 1][j];
            xp[u][j] = p;
        }
    }
    #pragma unroll
    for (int u = 0; u < 2; ++u)
        #pragma unroll
        for (int j = 0; j < 8; ++j)
            asm volatile("" : "+v"(xp[u][j]));   // discourage LDS remat

    float bestd[TPW];
    int   besti[TPW];
    #pragma unroll
    for (int t = 0; t < TPW; ++t) { bestd[t] = 3.4028235e38f; besti[t] = 0; }

    // ---- all 16 waves scan the SAME code stream in lockstep (L1 reuse x16) ----
    // dist' = k2 + sum x'_j k_j ; load-use (no dbuf regs), TLP hides latency
    const v2f* kb2 = (const v2f*)(keys + (size_t)c * K_CODES * D_CB);
    for (int ch = 0; ch < CHUNKS; ++ch) {
        const int o = ch * 256 + lane * 4;
        const v2f a0 = kb2[o];
        const v2f a1 = kb2[o + 1];
        const v2f a2 = kb2[o + 2];
        const v2f a3 = kb2[o + 3];

        const int code = ch * 64 + lane;
        float k2 = a0.x * a0.x;
        k2 = fmaf(a0.y, a0.y, k2);
        k2 = fmaf(a1.x, a1.x, k2);
        k2 = fmaf(a1.y, a1.y, k2);
        k2 = fmaf(a2.x, a2.x, k2);
        k2 = fmaf(a2.y, a2.y, k2);
        k2 = fmaf(a3.x, a3.x, k2);
        k2 = fmaf(a3.y, a3.y, k2);
        v2f k2p; k2p.x = k2; k2p.y = k2;

        #pragma unroll
        for (int u = 0; u < 2; ++u) {
            v2f d;
            PK_INIT(d, xp[u][0], a0, k2p);   // d = x0'*k0 + k2 (both halves)
            PK_HI (d, xp[u][1], a0);
            PK_LO (d, xp[u][2], a1);
            PK_HI (d, xp[u][3], a1);
            PK_LO (d, xp[u][4], a2);
            PK_HI (d, xp[u][5], a2);
            PK_LO (d, xp[u][6], a3);
            PK_HI (d, xp[u][7], a3);

            const int t0 = 2 * u, t1 = 2 * u + 1;
            const bool lt0 = d.x < bestd[t0];
            bestd[t0] = lt0 ? d.x : bestd[t0];
            besti[t0] = lt0 ? code : besti[t0];
            const bool lt1 = d.y < bestd[t1];
            bestd[t1] = lt1 ? d.y : bestd[t1];
            besti[t1] = lt1 ? code : besti[t1];
        }

        // keep the 16 waves within one L1 window (8 KB per 4 chunks);
        // raw s_barrier: purely temporal, no waitcnt drain
        if ((ch & 3) == 3) __builtin_amdgcn_s_barrier();
    }

    // ---- cross-lane argmin per tuple (tie -> smaller index == numpy) ----
    int myidx = 0;
    #pragma unroll
    for (int t = 0; t < TPW; ++t) {
        float d = bestd[t];
        int   i = besti[t];
        #pragma unroll
        for (int m = 32; m >= 1; m >>= 1) {
            const float od = __shfl_xor(d, m, 64);
            const int   oi = __shfl_xor(i, m, 64);
            if (od < d || (od == d && oi < i)) { d = od; i = oi; }
        }
        if (lane == t) myidx = i;
    }

    // ---- gather values row + scatter to output ----
    if (lane < TPW) {
        const int tg = h * 64 + wave * TPW + lane;   // tuple = b*16 + n
        const int b = tg >> 4, n = tg & 15;
        const float4* vr = (const float4*)(values + ((size_t)c * K_CODES + myidx) * D_CB);
        const float4 v0 = vr[0];
        const float4 v1 = vr[1];
        float* op = out + (size_t)b * 32768 + c * 128 + n;
        op[0]   = v0.x; op[16]  = v0.y; op[32]  = v0.z; op[48]  = v0.w;
        op[64]  = v1.x; op[80]  = v1.y; op[96]  = v1.z; op[112] = v1.w;
    }
}

extern "C" void kernel_launch(void* const* d_in, const int* in_sizes, int n_in,
                              void* d_out, int out_size, void* d_ws, size_t ws_size,
                              hipStream_t stream) {
    const float* emb    = (const float*)d_in[0];
    const float* keys   = (const float*)d_in[1];
    const float* values = (const float*)d_in[2];
    float* out = (float*)d_out;
    dkvb_kernel<<<2 * C_NUM, THREADS, 0, stream>>>(emb, keys, values, out);
}

// Round 14
// 45.125 us; speedup vs baseline: 1.1032x; 1.1032x over previous
//
#include <hip/hip_runtime.h>

#define C_NUM   256
#define K_CODES 4096
#define D_CB    8
#define THREADS 512
#define TPW     8                   // tuples per wave; 8 waves x 8 = 64 tuples/block
#define CHUNKS  64                  // every wave scans all 4096 codes, 64/chunk

typedef float v2f __attribute__((ext_vector_type(2)));
typedef float v4f __attribute__((ext_vector_type(4)));

// packed fp32 FMA: d = x * bcast(key-half) + d, tuple-pair in the two halves.
#define PK_INIT(d, x, kp, c) \
    asm("v_pk_fma_f32 %0, %1, %2, %3 op_sel:[0,0,0] op_sel_hi:[1,0,1]" \
        : "=v"(d) : "v"(x), "v"(kp), "v"(c))
#define PK_LO(d, x, kp) \
    asm("v_pk_fma_f32 %0, %1, %2, %0 op_sel:[0,0,0] op_sel_hi:[1,0,1]" \
        : "+v"(d) : "v"(x), "v"(kp))
#define PK_HI(d, x, kp) \
    asm("v_pk_fma_f32 %0, %1, %2, %0 op_sel:[0,1,0] op_sel_hi:[1,1,1]" \
        : "+v"(d) : "v"(x), "v"(kp))

__global__ __launch_bounds__(THREADS, 2)   // min-waves=2; larger values wreck the allocator (R3/R4/R7)
void dkvb_kernel(const float* __restrict__ emb,
                 const float* __restrict__ keys,
                 const float* __restrict__ values,
                 float* __restrict__ out) {
    __shared__ float xs[64][D_CB];   // 2 KB

    const int bid  = blockIdx.x;
    const int c    = bid & 255;      // codebook; bid and bid+256 share an XCD (256%8==0)
    const int h    = bid >> 8;       // tuple half: 0 -> tuples 0..63, 1 -> 64..127
    const int tid  = threadIdx.x;
    const int wave = tid >> 6;
    const int lane = tid & 63;

    // ---- stage this block's 64 tuples of x into LDS (one element/thread) ----
    // x[t][j] = emb[(t>>4)*32768 + c*128 + j*16 + (t&15)]
    {
        const int tl = tid >> 3, j = tid & 7;
        const int tg = h * 64 + tl;
        xs[tl][j] = emb[(size_t)(tg >> 4) * 32768 + c * 128 + j * 16 + (tg & 15)];
    }
    __syncthreads();

    // ---- x' = -2*x, tuple-PAIRED into VGPR float2s: xp[u][j] = (x'[2u][j], x'[2u+1][j]) ----
    v2f xp[4][8];
    #pragma unroll
    for (int u = 0; u < 4; ++u) {
        #pragma unroll
        for (int j = 0; j < 8; ++j) {
            v2f p;
            p.x = -2.0f * xs[wave * TPW + 2 * u][j];
            p.y = -2.0f * xs[wave * TPW + 2 * u + 1][j];
            xp[u][j] = p;
        }
    }
    // CLOBBER xs: rows are wave-local (writer tid -> row tid>>3 belongs to the
    // same wave that reads it), so in-wave program order guarantees all reads
    // above completed. With xs destroyed, the compiler CANNOT rematerialize
    // xp from LDS inside the chunk loop (R11/R12 pathology, VGPR=56).
    xs[tid >> 3][tid & 7] = 3.0e38f;

    float bestd[TPW];
    int   besti[TPW];
    #pragma unroll
    for (int t = 0; t < TPW; ++t) { bestd[t] = 3.4028235e38f; besti[t] = 0; }

    // ---- all 8 waves scan the SAME code stream in lockstep (L1 reuse) ----
    // dist' = k2 + sum x'_j k_j  (same per-tuple chain order as R12 -> identical rounding)
    const v4f* kb4 = (const v4f*)(keys + (size_t)c * K_CODES * D_CB);
    const int o = lane * 2;          // 2 float4 = one 8-float key row per lane
    v4f a0 = kb4[o], a1 = kb4[o + 1];
    for (int ch = 0; ch < CHUNKS; ++ch) {
        const int nco = ((ch + 1 < CHUNKS) ? (ch + 1) : ch) * 128 + o;
        const v4f b0 = kb4[nco];
        const v4f b1 = kb4[nco + 1];

        const int code = ch * 64 + lane;
        float k2 = a0.x * a0.x;
        k2 = fmaf(a0.y, a0.y, k2);
        k2 = fmaf(a0.z, a0.z, k2);
        k2 = fmaf(a0.w, a0.w, k2);
        k2 = fmaf(a1.x, a1.x, k2);
        k2 = fmaf(a1.y, a1.y, k2);
        k2 = fmaf(a1.z, a1.z, k2);
        k2 = fmaf(a1.w, a1.w, k2);
        v2f k2p; k2p.x = k2; k2p.y = k2;

        // register-pair views of the key row (no data movement)
        const v2f a01 = __builtin_shufflevector(a0, a0, 0, 1);
        const v2f a23 = __builtin_shufflevector(a0, a0, 2, 3);
        const v2f a45 = __builtin_shufflevector(a1, a1, 0, 1);
        const v2f a67 = __builtin_shufflevector(a1, a1, 2, 3);

        #pragma unroll
        for (int u = 0; u < 4; ++u) {
            v2f d;
            PK_INIT(d, xp[u][0], a01, k2p);   // d = x0'*k0 + k2 (both halves)
            PK_HI (d, xp[u][1], a01);
            PK_LO (d, xp[u][2], a23);
            PK_HI (d, xp[u][3], a23);
            PK_LO (d, xp[u][4], a45);
            PK_HI (d, xp[u][5], a45);
            PK_LO (d, xp[u][6], a67);
            PK_HI (d, xp[u][7], a67);

            const int t0 = 2 * u, t1 = 2 * u + 1;
            const bool lt0 = d.x < bestd[t0];
            bestd[t0] = lt0 ? d.x : bestd[t0];
            besti[t0] = lt0 ? code : besti[t0];
            const bool lt1 = d.y < bestd[t1];
            bestd[t1] = lt1 ? d.y : bestd[t1];
            besti[t1] = lt1 ? code : besti[t1];
        }
        a0 = b0; a1 = b1;

        // keep the 8 waves within one L1 window; raw s_barrier leaves prefetch in flight
        if ((ch & 3) == 3) __builtin_amdgcn_s_barrier();
    }

    // ---- cross-lane argmin per tuple (tie -> smaller index == numpy) ----
    int myidx = 0;
    #pragma unroll
    for (int t = 0; t < TPW; ++t) {
        float d = bestd[t];
        int   i = besti[t];
        #pragma unroll
        for (int m = 32; m >= 1; m >>= 1) {
            const float od = __shfl_xor(d, m, 64);
            const int   oi = __shfl_xor(i, m, 64);
            if (od < d || (od == d && oi < i)) { d = od; i = oi; }
        }
        if (lane == t) myidx = i;
    }

    // ---- gather values row + scatter to output ----
    if (lane < TPW) {
        const int tg = h * 64 + wave * TPW + lane;   // tuple = b*16 + n
        const int b = tg >> 4, n = tg & 15;
        const float4* vr = (const float4*)(values + ((size_t)c * K_CODES + myidx) * D_CB);
        const float4 v0 = vr[0];
        const float4 v1 = vr[1];
        float* op = out + (size_t)b * 32768 + c * 128 + n;
        op[0]   = v0.x; op[16]  = v0.y; op[32]  = v0.z; op[48]  = v0.w;
        op[64]  = v1.x; op[80]  = v1.y; op[96]  = v1.z; op[112] = v1.w;
    }
}

extern "C" void kernel_launch(void* const* d_in, const int* in_sizes, int n_in,
                              void* d_out, int out_size, void* d_ws, size_t ws_size,
                              hipStream_t stream) {
    const float* emb    = (const float*)d_in[0];
    const float* keys   = (const float*)d_in[1];
    const float* values = (const float*)d_in[2];
    float* out = (float*)d_out;
    dkvb_kernel<<<2 * C_NUM, THREADS, 0, stream>>>(emb, keys, values, out);
}